// Round 4
// baseline (477.052 us; speedup 1.0000x reference)
//
#include <hip/hip_runtime.h>
#include <stdint.h>

#define BATCH 64
#define H 512
#define W 512
#define NR 256
#define ROWS_PER_BLOCK 16
#define THREADS 256
#define PASSES (ROWS_PER_BLOCK / 2)

// LDS aperture: low 32 bits of a generic pointer to __shared__ = LDS offset.
__device__ __forceinline__ uint32_t lds_off(const void* p) {
    return (uint32_t)(uintptr_t)p;
}

// Native fire-and-forget LDS fp32 adds into 4 component tables spaced NR*4 B
// apart. Within one instruction, lanes differ by ring (4 B stride) -> spread
// across all 32 banks.
__device__ __forceinline__ void lds_add4(uint32_t addr, float v0, float v1,
                                         float v2, float v3) {
    asm volatile(
        "ds_add_f32 %0, %1\n\t"
        "ds_add_f32 %0, %2 offset:1024\n\t"
        "ds_add_f32 %0, %3 offset:2048\n\t"
        "ds_add_f32 %0, %4 offset:3072"
        :: "v"(addr), "v"(v0), "v"(v1), "v"(v2), "v"(v3) : "memory");
}

__device__ __forceinline__ void gl_add(float* p, float v) {
    asm volatile("global_atomic_add_f32 %0, %1, off"
                 :: "v"(p), "v"(v) : "memory");
}

__global__ __launch_bounds__(THREADS) void frc_accum(
    const float* __restrict__ f1r, const float* __restrict__ f1i,
    const float* __restrict__ f2r, const float* __restrict__ f2i,
    float* __restrict__ gacc /* [BATCH][4][NR] */)
{
    __shared__ float s_acc[4 * NR];   // [comp][ring], 4 KiB -> high occupancy
    for (int i = threadIdx.x; i < 4 * NR; i += THREADS) s_acc[i] = 0.0f;
    __syncthreads();

    const int b    = blockIdx.y;
    const int row0 = blockIdx.x * ROWS_PER_BLOCK;
    const int tid  = threadIdx.x;
    const int x0   = (tid & 127) * 4;       // 128 threads cover one row
    const int rsub = tid >> 7;              // 0 or 1: two rows per pass
    const uint32_t sbase = lds_off(s_acc);

    const size_t img = (size_t)b * H * W + (size_t)x0;

    // ---- software pipeline: pass p+1's loads issue before pass p's flushes ----
    size_t base = img + (size_t)(row0 + rsub) * W;
    float4 c1r = *(const float4*)(f1r + base);
    float4 c1i = *(const float4*)(f1i + base);
    float4 c2r = *(const float4*)(f2r + base);
    float4 c2i = *(const float4*)(f2i + base);

    #pragma unroll
    for (int p = 0; p < PASSES; ++p) {
        float4 n1r, n1i, n2r, n2i;
        if (p + 1 < PASSES) {
            const size_t nb = img + (size_t)(row0 + 2 * (p + 1) + rsub) * W;
            n1r = *(const float4*)(f1r + nb);
            n1i = *(const float4*)(f1i + nb);
            n2r = *(const float4*)(f2r + nb);
            n2i = *(const float4*)(f2i + nb);
        }

        const int y = row0 + 2 * p + rsub;
        const float fdy = (float)(y - 256);
        const float dy2 = fdy * fdy;

        const float a1[4] = {c1r.x, c1r.y, c1r.z, c1r.w};
        const float b1[4] = {c1i.x, c1i.y, c1i.z, c1i.w};
        const float a2[4] = {c2r.x, c2r.y, c2r.z, c2r.w};
        const float b2[4] = {c2i.x, c2i.y, c2i.z, c2i.w};

        float acr = 0.f, aci = 0.f, ap1 = 0.f, ap2 = 0.f;
        int cur = -1;

        #pragma unroll
        for (int j = 0; j < 4; ++j) {
            const float fdx = (float)(x0 + j - 256);
            const float r2  = fdx * fdx + dy2;   // exact integer < 2^18
            const int bin   = (int)sqrtf(r2);    // floor(sqrt), fp32-safe here

            const float cr = a1[j] * a2[j] + b1[j] * b2[j];
            const float ci = b1[j] * a2[j] - a1[j] * b2[j];
            const float p1 = a1[j] * a1[j] + b1[j] * b1[j];
            const float p2 = a2[j] * a2[j] + b2[j] * b2[j];

            if (bin != cur) {
                if (cur >= 0 && cur < NR)
                    lds_add4(sbase + 4u * (uint32_t)cur, acr, aci, ap1, ap2);
                acr = 0.f; aci = 0.f; ap1 = 0.f; ap2 = 0.f;
                cur = bin;
            }
            acr += cr; aci += ci; ap1 += p1; ap2 += p2;
        }
        if (cur >= 0 && cur < NR)
            lds_add4(sbase + 4u * (uint32_t)cur, acr, aci, ap1, ap2);

        if (p + 1 < PASSES) {
            c1r = n1r; c1i = n1i; c2r = n2r; c2i = n2i;
        }
    }

    // asm's LDS ops are invisible to the compiler — drain before the barrier.
    asm volatile("s_waitcnt lgkmcnt(0)" ::: "memory");
    __syncthreads();

    // One thread per ring: stride-1, conflict-free merge to global.
    const int r = tid;  // THREADS == NR
    const float s0 = s_acc[0 * NR + r];
    const float s1 = s_acc[1 * NR + r];
    const float s2 = s_acc[2 * NR + r];
    const float s3 = s_acc[3 * NR + r];
    if (s0 != 0.f || s1 != 0.f || s2 != 0.f || s3 != 0.f) {
        float* g = gacc + (size_t)b * 4 * NR + r;
        gl_add(g + 0 * NR, s0);
        gl_add(g + 1 * NR, s1);
        gl_add(g + 2 * NR, s2);
        gl_add(g + 3 * NR, s3);
    }
}

__global__ __launch_bounds__(NR) void frc_finalize(
    const float* __restrict__ gacc, float* __restrict__ out)
{
    const int b = blockIdx.x;
    const int r = threadIdx.x;
    const float* g = gacc + (size_t)b * 4 * NR + r;
    const float cr = g[0 * NR], ci = g[1 * NR], p1 = g[2 * NR], p2 = g[3 * NR];
    const float num = sqrtf(cr * cr + ci * ci);
    const float den = sqrtf(p1 * p2);
    out[(size_t)b * NR + r] = (den == 0.f) ? 0.f : num / den;
}

extern "C" void kernel_launch(void* const* d_in, const int* in_sizes, int n_in,
                              void* d_out, int out_size, void* d_ws, size_t ws_size,
                              hipStream_t stream) {
    const float* f1r = (const float*)d_in[0];
    const float* f1i = (const float*)d_in[1];
    const float* f2r = (const float*)d_in[2];
    const float* f2i = (const float*)d_in[3];
    float* out  = (float*)d_out;
    float* gacc = (float*)d_ws;   // BATCH*4*NR floats = 256 KiB

    (void)in_sizes; (void)n_in; (void)out_size; (void)ws_size;

    hipMemsetAsync(gacc, 0, (size_t)BATCH * 4 * NR * sizeof(float), stream);

    dim3 grid(H / ROWS_PER_BLOCK, BATCH);  // 32 x 64 = 2048 blocks
    frc_accum<<<grid, THREADS, 0, stream>>>(f1r, f1i, f2r, f2i, gacc);
    frc_finalize<<<dim3(BATCH), dim3(NR), 0, stream>>>(gacc, out);
}